// Round 7
// baseline (390.132 us; speedup 1.0000x reference)
//
#include <hip/hip_runtime.h>

// ---------------------------------------------------------------------------
// FlashMMSequenceMixing (Hyena-style): B=8, L=2048, D=768, ORDER=128, FFT=4096
// R13 -> R14:
//  1) mode-0 GEMM rewritten as "B-direct": A stays on the global_load_lds +
//     XOR-swizzle path; B fragments are loaded straight to VGPRs from global
//     (L2-hot: concurrently-live B panels per XCD ~3MB < 4MB L2), double
//     buffered 2 tiles ahead. Halves LDS traffic (the measured ~864 LDS-clk
//     vs 466 MFMA-clk per-tile imbalance), 1 barrier/tile (was 4), counted
//     vmcnt fences.
//     Pipeline (per-wave vmcnt stream, oldest->newest):
//       prologue: A0(3) B0(8) A1(3) B1(8); fence vmcnt(11) = A0,B0 landed.
//       tile 0: compute(buf0,bR0); issue B2->bR0; fence vmcnt(8) [A1,B1 in].
//       tiles 1..9: issue A@t+1(3); compute(buf t%2, bR t%2); issue
//         B@t+2(8) -> same bR (reg WAR: after last MFMA use, compiler-held);
//         fence vmcnt(8): in-flight B@t+1(8)+A@t+1(3)+B@t+2(8)=19, completes
//         oldest 11 = B@t+1 + A@t+1 = exactly what tile t+1 reads.
//       tile 10: issue A@11; compute; fence vmcnt(0) (drain; nothing issued
//         after -> vmcnt==0 at s_endpgm).
//       tile 11: compute only.
//     LDS WAR: A@t+1 DMA (issued at tile-t start) targets buf^1, whose
//     readers drained at the previous fence's lgkmcnt(0)+barrier.
//  2) mode-1 reverted to R12's 2-phase kernel (suspected source of the
//     348->361 wall regression when both modes went 8-phase in R13).
// fft_conv/filters unchanged from R11/R12.
// ---------------------------------------------------------------------------

typedef __bf16 bf16x8 __attribute__((ext_vector_type(8)));
typedef float  f32x4  __attribute__((ext_vector_type(4)));

#define AS1 __attribute__((address_space(1)))
#define AS3 __attribute__((address_space(3)))
#define GLD16(gp, lp) __builtin_amdgcn_global_load_lds((AS1 void*)(void*)(gp), (AS3 void*)(void*)(lp), 16, 0, 0)

// compiler-visible fences (memory clobber pins LDS/global ops to program order)
#define LGKM_BAR       __asm__ __volatile__("s_waitcnt lgkmcnt(0)\n\ts_barrier" ::: "memory")
#define VM_LGKM_BAR(N) __asm__ __volatile__("s_waitcnt vmcnt(" #N ") lgkmcnt(0)\n\ts_barrier" ::: "memory")

__device__ __forceinline__ unsigned short f2b(float f) {
    unsigned u = __builtin_bit_cast(unsigned, f);
    unsigned r = (u + 0x7fffu + ((u >> 16) & 1u)) >> 16;
    return (unsigned short)r;
}
__device__ __forceinline__ float b2f_lo(unsigned u) {
    return __builtin_bit_cast(float, u << 16);
}
__device__ __forceinline__ float b2f_hi(unsigned u) {
    return __builtin_bit_cast(float, u & 0xffff0000u);
}

__device__ __forceinline__ float2 cmul(float2 a, float2 b) {
    return make_float2(a.x * b.x - a.y * b.y, a.x * b.y + a.y * b.x);
}
__device__ __forceinline__ float2 cadd(float2 a, float2 b) { return make_float2(a.x + b.x, a.y + b.y); }
__device__ __forceinline__ float2 csub(float2 a, float2 b) { return make_float2(a.x - b.x, a.y - b.y); }

#define TWO_PI 6.283185307179586f

// ------------------------- 16-point register DFT ---------------------------
#define BFLY(i,j)   { float2 ta=x[i], tb=x[j]; x[i]=cadd(ta,tb); x[j]=csub(ta,tb); }
#define BFLYW(i,j,w){ float2 ta=x[i], tb=x[j]; x[i]=cadd(ta,tb); x[j]=cmul(csub(ta,tb),(w)); }
#define BFLYI(i,j)  { float2 ta=x[i], tb=x[j]; x[i]=cadd(ta,tb); float2 tt=csub(ta,tb); x[j]=make_float2(-dd*tt.y, dd*tt.x); }
#define CSWAP(i,j)  { float2 tt=x[i]; x[i]=x[j]; x[j]=tt; }

template<int DIR, bool UZ>
__device__ __forceinline__ void dft16(float2* x) {
    const float dd = (float)DIR;
    const float C1 = 0.92387953251128674f, S1 = 0.38268343236508977f, R2 = 0.70710678118654752f;
    const float2 W1 = make_float2( C1, dd*S1);
    const float2 W2 = make_float2( R2, dd*R2);
    const float2 W3 = make_float2( S1, dd*C1);
    const float2 W5 = make_float2(-S1, dd*C1);
    const float2 W6 = make_float2(-R2, dd*R2);
    const float2 W7 = make_float2(-C1, dd*S1);
    if (UZ) {
        x[8]  = x[0];
        x[9]  = cmul(x[1], W1);
        x[10] = cmul(x[2], W2);
        x[11] = cmul(x[3], W3);
        x[12] = make_float2(-dd*x[4].y, dd*x[4].x);
        x[13] = cmul(x[5], W5);
        x[14] = cmul(x[6], W6);
        x[15] = cmul(x[7], W7);
    } else {
        BFLY(0,8); BFLYW(1,9,W1); BFLYW(2,10,W2); BFLYW(3,11,W3);
        BFLYI(4,12); BFLYW(5,13,W5); BFLYW(6,14,W6); BFLYW(7,15,W7);
    }
    BFLY(0,4);  BFLYW(1,5,W2);  BFLYI(2,6);   BFLYW(3,7,W6);
    BFLY(8,12); BFLYW(9,13,W2); BFLYI(10,14); BFLYW(11,15,W6);
    BFLY(0,2);  BFLYI(1,3);  BFLY(4,6);   BFLYI(5,7);
    BFLY(8,10); BFLYI(9,11); BFLY(12,14); BFLYI(13,15);
    BFLY(0,1); BFLY(2,3); BFLY(4,5); BFLY(6,7);
    BFLY(8,9); BFLY(10,11); BFLY(12,13); BFLY(14,15);
    CSWAP(1,8); CSWAP(2,4); CSWAP(3,12); CSWAP(5,10); CSWAP(7,14); CSWAP(11,13);
}

// twiddle by power-split: x[4a+b] *= w^(4a) * w^b. 6 complex (12 VGPR) live.
__device__ __forceinline__ void twiddle16(float2* x, float ang) {
    float s, c; __sincosf(ang, &s, &c);
    const float2 u1  = make_float2(c, s);
    const float2 u2  = cmul(u1, u1);
    const float2 u3  = cmul(u2, u1);
    const float2 u4  = cmul(u2, u2);
    const float2 u8  = cmul(u4, u4);
    const float2 u12 = cmul(u8, u4);
    x[1]  = cmul(x[1],  u1);
    x[2]  = cmul(x[2],  u2);
    x[3]  = cmul(x[3],  u3);
    x[4]  = cmul(x[4],  u4);
    x[5]  = cmul(x[5],  cmul(u4, u1));
    x[6]  = cmul(x[6],  cmul(u4, u2));
    x[7]  = cmul(x[7],  cmul(u4, u3));
    x[8]  = cmul(x[8],  u8);
    x[9]  = cmul(x[9],  cmul(u8, u1));
    x[10] = cmul(x[10], cmul(u8, u2));
    x[11] = cmul(x[11], cmul(u8, u3));
    x[12] = cmul(x[12], u12);
    x[13] = cmul(x[13], cmul(u12, u1));
    x[14] = cmul(x[14], cmul(u12, u2));
    x[15] = cmul(x[15], cmul(u12, u3));
}

// physical LDS index (float2 units), XOR-swizzled exact-stride layouts.
__device__ __forceinline__ int ph1(int row, int col) { return row * 256 + (col ^ row); }
__device__ __forceinline__ int ph2(int row, int col) { return row * 16 + (col ^ (row & 15)); }

__device__ __forceinline__ void fft4096_fwd(float2* x, float2* lds, int t) {
    dft16<-1, true>(x);
    twiddle16(x, -(float)t * (TWO_PI / 4096.0f));
    #pragma unroll
    for (int k1 = 0; k1 < 16; ++k1) lds[ph1(k1, t)] = x[k1];
    __syncthreads();
    const int hi = t >> 4, lo = t & 15;
    #pragma unroll
    for (int t1 = 0; t1 < 16; ++t1) x[t1] = lds[ph1(hi, t1 * 16 + lo)];
    dft16<-1, false>(x);
    twiddle16(x, -(float)lo * (TWO_PI / 256.0f));
    __syncthreads();
    #pragma unroll
    for (int k2 = 0; k2 < 16; ++k2) lds[ph2(t, k2)] = x[k2];
    __syncthreads();
    #pragma unroll
    for (int t0 = 0; t0 < 16; ++t0) x[t0] = lds[ph2(hi * 16 + t0, lo)];
    dft16<-1, false>(x);
}

__device__ __forceinline__ void fft4096_inv(float2* x, float2* lds, int t) {
    const int hi = t >> 4, lo = t & 15;
    dft16<1, false>(x);
    __syncthreads();
    #pragma unroll
    for (int t0 = 0; t0 < 16; ++t0) lds[ph2(hi * 16 + t0, lo)] = x[t0];
    __syncthreads();
    #pragma unroll
    for (int k2 = 0; k2 < 16; ++k2) x[k2] = lds[ph2(t, k2)];
    twiddle16(x, (float)lo * (TWO_PI / 256.0f));
    dft16<1, false>(x);
    __syncthreads();
    #pragma unroll
    for (int t1 = 0; t1 < 16; ++t1) lds[ph1(hi, t1 * 16 + lo)] = x[t1];
    __syncthreads();
    #pragma unroll
    for (int k1 = 0; k1 < 16; ++k1) x[k1] = lds[ph1(k1, t)];
    twiddle16(x, (float)t * (TWO_PI / 4096.0f));
    dft16<1, false>(x);
}

// ------------------------------- filter MLP --------------------------------
__global__ __launch_bounds__(256) void filter_k_kernel(
    const float* __restrict__ z, const float* __restrict__ sf,
    const float* __restrict__ eo, const float* __restrict__ eo_b,
    const float* __restrict__ oo1, const float* __restrict__ oo1_b,
    const float* __restrict__ oo2, const float* __restrict__ oo2_b,
    const float* __restrict__ oh, float* __restrict__ kfil)
{
    __shared__ float h3buf[4][128];
    __shared__ float htmp[2][128];
    const int t = threadIdx.x;
    const int l0 = blockIdx.x * 4;
    const int half = t >> 7;
    const int o = t & 127;
    const float sfo = sf[o];
    for (int p = 0; p < 2; ++p) {
        const int li = p * 2 + half;
        const int l = l0 + li;
        float a = eo_b[o];
        #pragma unroll
        for (int e = 0; e < 5; ++e) a += z[l * 5 + e] * eo[e * 128 + o];
        htmp[half][o] = sinf(sfo * a);
        __syncthreads();
        float a2 = oo1_b[o];
        for (int q = 0; q < 128; ++q) a2 += htmp[half][q] * oo1[q * 128 + o];
        const float h2 = sinf(sfo * a2);
        __syncthreads();
        htmp[half][o] = h2;
        __syncthreads();
        float a3 = oo2_b[o];
        for (int q = 0; q < 128; ++q) a3 += htmp[half][q] * oo2[q * 128 + o];
        h3buf[li][o] = sinf(sfo * a3);
        __syncthreads();
    }
    const float MIND = -3.070113457325394f;
    const float MAXD = -15.350567286626972f;
    for (int c = 0; c < 3; ++c) {
        const int h = t + c * 256;
        float acc[4];
        #pragma unroll
        for (int li = 0; li < 4; ++li) acc[li] = 0.f;
        for (int q = 0; q < 128; ++q) {
            const float w = oh[q * 768 + h];
            #pragma unroll
            for (int li = 0; li < 4; ++li) acc[li] += h3buf[li][q] * w;
        }
        const float delta = fabsf(MIND + (MAXD - MIND) * (float)h * (1.0f / 767.0f));
        #pragma unroll
        for (int li = 0; li < 4; ++li) {
            const int l = l0 + li;
            const float tt = (float)l * (1.0f / 2047.0f);
            kfil[h * 2048 + l] = acc[li] * expf(-tt * delta);
        }
    }
}

// --------------------------- filter FFT ------------------------------------
// Stores Kf' = (FFT(k) + D_bias[d]) / 4096 (normalization + skip folded in).
__global__ __launch_bounds__(256) void filter_fft_kernel(
    const float* __restrict__ kfil, const float* __restrict__ D_bias,
    float2* __restrict__ Kf)
{
    __shared__ __align__(16) float2 lds[4096];
    const int d = blockIdx.x, t = threadIdx.x;
    float2 x[16];
    #pragma unroll
    for (int r = 0; r < 8; ++r) x[r] = make_float2(kfil[d * 2048 + r * 256 + t], 0.f);
    fft4096_fwd(x, lds, t);
    const float db = D_bias[d];
    const float s = 1.0f / 4096.0f;
    #pragma unroll
    for (int k3 = 0; k3 < 16; ++k3)
        Kf[d * 4096 + k3 * 256 + t] = make_float2((x[k3].x + db) * s, x[k3].y * s);
}

// --------------------------- conversions/transposes ------------------------
__global__ __launch_bounds__(256) void convert_u_kernel(
    const float* __restrict__ u, unsigned short* __restrict__ ub)
{
    const int g = blockIdx.x * 256 + threadIdx.x;
    const float4 v = ((const float4*)u)[g];
    uint2 o;
    o.x = (unsigned)f2b(v.x) | ((unsigned)f2b(v.y) << 16);
    o.y = (unsigned)f2b(v.z) | ((unsigned)f2b(v.w) << 16);
    ((uint2*)ub)[g] = o;
}

__global__ __launch_bounds__(256) void transpose_W_kernel(
    const float* __restrict__ W, unsigned short* __restrict__ Wt, int K, int N)
{
    __shared__ float tile[32][33];
    const int n0 = blockIdx.x * 32, k0 = blockIdx.y * 32;
    const int tx = threadIdx.x & 31, ty = threadIdx.x >> 5;
    #pragma unroll
    for (int r = 0; r < 4; ++r) {
        const int kk = ty + r * 8;
        tile[kk][tx] = W[(k0 + kk) * N + n0 + tx];
    }
    __syncthreads();
    #pragma unroll
    for (int r = 0; r < 4; ++r) {
        const int nn = ty + r * 8;
        Wt[(n0 + nn) * K + k0 + tx] = f2b(tile[tx][nn]);
    }
}

__global__ __launch_bounds__(256) void transpose_Y_kernel(
    const unsigned short* __restrict__ Y, unsigned short* __restrict__ Yt)
{
    __shared__ unsigned short tile[32][34];
    const int bx = blockIdx.x;
    const int l0 = (bx & 63) * 32;
    const int tmp = bx >> 6;
    const int d0 = (tmp % 24) * 32;
    const int b  = tmp / 24;
    const int tx = threadIdx.x & 31, ty = threadIdx.x >> 5;
    #pragma unroll
    for (int r = 0; r < 4; ++r) {
        const int dd = ty + r * 8;
        tile[dd][tx] = Y[(b * 768 + d0 + dd) * 2048 + l0 + tx];
    }
    __syncthreads();
    #pragma unroll
    for (int r = 0; r < 4; ++r) {
        const int ll = ty + r * 8;
        Yt[(b * 2048 + l0 + ll) * 768 + d0 + tx] = tile[tx][ll];
    }
}

// --------------------- bf16 GEMM, mode 0: B-direct -------------------------
// 192x256 tile, BK=64, 8 waves (2Mx4N), wave tile 96x64.
// A: global_load_lds + XOR chunk swizzle, LDS [2][192][64] (48KB).
// B: direct global->VGPR fragment loads, 2 tiles ahead, double reg buffer.
// Grid (64, 12) = 768 blocks = 3.0 rounds at 1 block/CU.
__global__ __launch_bounds__(512, 2) void gemm_bd_kernel(
    const unsigned short* __restrict__ A,
    const unsigned short* __restrict__ Bm,
    const float* __restrict__ bias,
    unsigned short* __restrict__ outb)
{
    extern __shared__ __align__(16) unsigned short lds[];
    unsigned short* As = lds;                 // [2][192][64]
    const int t = threadIdx.x;
    const int wv = t >> 6, lane = t & 63;
    const int row0 = blockIdx.y * 192;
    const int col0 = blockIdx.x * 256;
    const int wr = wv >> 2, wc = wv & 3;      // 2M x 4N
    const int frow = lane & 15, kc = lane >> 4;

    f32x4 acc[6][4] = {};

    // A staging: thread t covers (row = q*64 + (t>>3), slot = t&7); slot
    // holds data chunk (t&7) ^ (row&7).
    const int srow = t >> 3;
    const int cdat = (t & 7) ^ (srow & 7);
    const unsigned short* gA = A + (row0 + srow) * 768 + cdat * 8;

#define STG_A(buf, kt)                                                        \
    { _Pragma("unroll") for (int q = 0; q < 3; ++q)                           \
        GLD16(gA + q * 49152 + (kt) * 64,                                     \
              (char*)As + (buf) * 24576 + q * 8192 + wv * 1024); }

    // B fragment lane pointer: col = col0 + wc*64 + n*16 + frow, k-piece kc.
    const unsigned short* pB = Bm + (size_t)(col0 + wc * 64 + frow) * 768 + kc * 8;
    bf16x8 bR0[4][2], bR1[4][2];

#define LOADB(BR, tt)                                                         \
    { _Pragma("unroll") for (int n = 0; n < 4; ++n) {                         \
        BR[n][0] = *(const bf16x8*)(pB + (size_t)n * 12288 + (tt) * 64);      \
        BR[n][1] = *(const bf16x8*)(pB + (size_t)n * 12288 + (tt) * 64 + 32); \
    } }

    // compute one M-half (3 frags) of a tile against a B reg buffer
#define COMPUTE_HALF(bufbit, BR, mh)                                          \
    {                                                                         \
        bf16x8 aF[3][2];                                                      \
        _Pragma("unroll") for (int m = 0; m < 3; ++m) {                       \
            const int r = wr * 96 + ((mh) * 3 + m) * 16 + frow;               \
            aF[m][0] = *(const bf16x8*)(As + (bufbit) * 12288 + r * 64 +      \
                                        (((0 + kc) ^ (r & 7)) << 3));         \
            aF[m][1] = *(const bf16x8*)(As + (bufbit) * 12288 + r * 64 +      \
                                        (((4 + kc) ^ (r & 7)) << 3));         \
        }                                                                     \
        __builtin_amdgcn_s_setprio(1);                                        \
        _Pragma("unroll") for (int m = 0; m < 3; ++m)                         \
        _Pragma("unroll") for (int n = 0; n < 4; ++n)                         \
        _Pragma("unroll") for (int ks = 0; ks < 2; ++ks)                      \
            acc[(mh) * 3 + m][n] = __builtin_amdgcn_mfma_f32_16x16x32_bf16(   \
                aF[m][ks], BR[n][ks], acc[(mh) * 3 + m][n], 0, 0, 0);         \
        __builtin_amdgcn_s_setprio(0);                                        \
    }

    // prologue: A0(3) B0(8) A1(3) B1(8); fence vmcnt(11) -> A0,B0 landed
    STG_A(0, 0);
    LOADB(bR0, 0);
    STG_A(1, 1);
    LOADB(bR1, 1);
    VM_LGKM_BAR(11);

    // tile 0 (buf0, bR0): no A issue (A1 in prologue); prefetch B2 -> bR0
    COMPUTE_HALF(0, bR0, 0); COMPUTE_HALF(0, bR0, 1);
    LOADB(bR0, 2);
    VM_LGKM_BAR(8);   // completes A1,B1; leaves B2(8)

    // tiles 1..8 in odd/even pairs
    #pragma unroll 1
    for (int i = 0; i < 4; ++i) {
        const int to = 2 * i + 1, te = 2 * i + 2;
        // odd tile (buf1, bR1)
        STG_A(0, to + 1);
        COMPUTE_HALF(1, bR1, 0); COMPUTE_HALF(1, bR1, 1);
        LOADB(bR1, to + 2);
        VM_LGKM_BAR(8);   // completes B@to+1 + A@to+1; leaves B@to+2
        // even tile (buf0, bR0)
        STG_A(1, te + 1);
        COMPUTE_HALF(0, bR0, 0); COMPUTE_HALF(0, bR0, 1);
        LOADB(bR0, te + 2);
        VM_LGKM_BAR(8);
    }

    // tile 9 (buf1, bR1): stage A@10, prefetch B@11
    STG_A(0, 10);
    COMPUTE_HALF(1, bR1, 0); COMPUTE_HALF(1, bR1, 1);
    LOADB(bR1, 11);
    VM_LGKM_BAR(8);   // completes B@10 + A@10; leaves B@11

    // tile 10 (buf0, bR0): stage A@11; drain everything
    STG_A(1, 11);
    COMPUTE_HALF(0, bR0, 0); COMPUTE_HALF(0, bR0, 1);
    VM_LGKM_BAR(0);   // A@11, B@11 landed; vmcnt==0 from here on

    // tile 11 (buf1, bR1)
    COMPUTE_HALF(1, bR1, 0); COMPUTE_HALF(1, bR1, 1);
#undef STG_A
#undef LOADB
#undef COMPUTE_HALF

    // epilogue: bf16 out to X[part][b][768][2048]
    {
        const int part = row0 / 768;       // 192 | 768: no straddle
        const int bb = col0 / 2048;        // 256 | 2048
        unsigned short* Xp = outb + (size_t)(part * 8 + bb) * 768 * 2048;
        const int drow0 = row0 - part * 768 + wr * 96 + kc * 4;
        const int lcol0 = col0 - bb * 2048 + wc * 64 + frow;
        #pragma unroll
        for (int m = 0; m < 6; ++m) {
            #pragma unroll
            for (int rr = 0; rr < 4; ++rr) {
                const int dd = drow0 + m * 16 + rr;
                const float bn = bias[row0 + wr * 96 + kc * 4 + m * 16 + rr];
                #pragma unroll
                for (int n = 0; n < 4; ++n)
                    Xp[dd * 2048 + lcol0 + n * 16] = f2b(acc[m][n][rr] + bn);
            }
        }
    }
}

// --------------------- bf16 GEMM, mode 1: 2-phase (R12) --------------------
// 256x192 tile, BK=64, 8 waves (4Mx2N), 2-phase double-buffered K-loop.
// Grid (64, 4) = 256 blocks = 1.0 round. f32 out [M][768].
template<int TM, int TN, int WR, int WC>
__global__ __launch_bounds__(512, 2) void gemm2ph_kernel(
    const unsigned short* __restrict__ A,
    const unsigned short* __restrict__ Bm,
    const float* __restrict__ bias,
    float* __restrict__ outf)
{
    constexpr int MF = TM / WR / 16;
    constexpr int NF = TN / WC / 16;
    constexpr int QA = TM / 64;
    constexpr int QB = TN / 64;
    extern __shared__ __align__(16) unsigned short lds[];
    unsigned short* As = lds;                    // [2][TM][64]
    unsigned short* Bs = lds + 2 * TM * 64;      // [2][TN][64]
    const int t = threadIdx.x;
    const int wv = t >> 6, lane = t & 63;
    const int row0 = blockIdx.x * TM;
    const int col0 = blockIdx.y * TN;
    const int wr = wv / WC, wc = wv % WC;
    const int frow = lane & 15, kc = lane >> 4;

    f32x4 acc[MF][NF] = {};

    const int srow = t >> 3;
    const int cdat = (t & 7) ^ (srow & 7);
    const unsigned short* gA = A  + (row0 + srow) * 768 + cdat * 8;
    const unsigned short* gB = Bm + (col0 + srow) * 768 + cdat * 8;

#define STAGE(buf, kt)                                                        \
    {                                                                         \
        _Pragma("unroll") for (int q = 0; q < QA; ++q)                        \
            GLD16(gA + q * 49152 + (kt) * 64,                                 \
                  (char*)As + (buf) * (TM * 128) + q * 8192 + wv * 1024);     \
        _Pragma("unroll") for (int q = 0; q < QB; ++q)                        \
            GLD16(gB + q * 49152 + (kt) * 64,                                 \
                  (char*)Bs + (buf) * (TN * 128) + q * 8192 + wv * 1024);     \
    }

#define HALF(buf, ks)                                                         \
    {                                                                         \
        bf16x8 aF[MF], bF[NF];                                                \
        _Pragma("unroll") for (int m = 0; m < MF; ++m) {                      \
            const int r = wr * (TM / WR) + m * 16 + frow;                     \
            aF[m] = *(const bf16x8*)(As + (buf) * (TM * 64) + r * 64 +        \
                                     ((((ks) * 4 + kc) ^ (r & 7)) << 3));     \
        }                                                                     \
        _Pragma("unroll") for (int n = 0; n < NF; ++n) {                      \
            const int r = wc * (TN / WC) + n * 16 + frow;                     \
            bF[n] = *(const bf16x8*)(Bs + (buf) * (TN * 64) + r * 64 +        \
                                     ((((ks) * 4 + kc) ^ (r & 7)) << 3));     \
        }                                                                     \
        __builtin_amdgcn_s_setprio(1);                                        \
        _Pragma("unroll") for (int m = 0; m < MF; ++m)                        \
        _Pragma("unroll") for (int n = 0; n < NF; ++n)                        \
            acc[m][n] = __builtin_amdgcn_mfma_f32_16x16x32_bf16(              \
                aF[m], bF[n], acc[m][n], 0, 0, 0);                            \
        __builtin_amdgcn_s_setprio(0);                                        \
    }

    STAGE(0, 0);
    STAGE(1, 1);
    VM_LGKM_BAR(7);            // oldest QA+QB(=7) = tile 0 landed

    HALF(0, 0); HALF(0, 1);
    VM_LGKM_BAR(0);            // tile 1 landed; buf0 readers done

    #pragma unroll 1
    for (int kt = 1; kt <= 9; kt += 2) {
        STAGE(0, kt + 1);
        HALF(1, 0); HALF(1, 1);
        VM_LGKM_BAR(0);
        STAGE(1, kt + 2);
        HALF(0, 0); HALF(0, 1);
        VM_LGKM_BAR(0);
    }

    HALF(1, 0); HALF(1, 1);
#undef STAGE
#undef HALF

    #pragma unroll
    for (int m = 0; m < MF; ++m) {
        #pragma unroll
        for (int rr = 0; rr < 4; ++rr) {
            const int mm = row0 + wr * (TM / WR) + kc * 4 + m * 16 + rr;
            #pragma unroll
            for (int n = 0; n < NF; ++n) {
                const int nn = col0 + wc * (TN / WC) + n * 16 + frow;
                outf[(size_t)mm * 768 + nn] = acc[m][n][rr] + bias[nn];
            }
        }
    }
}

// --------------------- fused conv4 + gate + FFT conv -----------------------
__device__ __forceinline__ void conv6(const unsigned short* __restrict__ p,
                                      const float* w, float bias, int t, float* out8)
{
    const uint4 m = *(const uint4*)(p + 8 * t);
    uint2 q = make_uint2(0u, 0u);
    if (t) q = *(const uint2*)(p + 8 * t - 4);
    float s[12];
    s[0] = b2f_lo(q.x); s[1] = b2f_hi(q.x); s[2] = b2f_lo(q.y); s[3] = b2f_hi(q.y);
    s[4] = b2f_lo(m.x); s[5] = b2f_hi(m.x); s[6] = b2f_lo(m.y); s[7] = b2f_hi(m.y);
    s[8] = b2f_lo(m.z); s[9] = b2f_hi(m.z); s[10] = b2f_lo(m.w); s[11] = b2f_hi(m.w);
    #pragma unroll
    for (int i = 0; i < 8; ++i)
        out8[i] = bias + w[0] * s[i + 1] + w[1] * s[i + 2] + w[2] * s[i + 3] + w[3] * s[i + 4];
}

// grid (768, 4): x=d (same-d blocks 768 apart -> same XCD -> Kf L2 reuse)
__global__ __launch_bounds__(256) void fft_conv_kernel(
    const unsigned short* __restrict__ X, const float2* __restrict__ Kf,
    const float* __restrict__ x1_s, const float* __restrict__ x2_s, const float* __restrict__ v_s,
    const float* __restrict__ x1_sb, const float* __restrict__ x2_sb, const float* __restrict__ v_sb,
    unsigned short* __restrict__ Y)
{
    __shared__ __align__(16) float2 lds[4096];
    unsigned* ldsu = (unsigned*)lds;
    const int d = blockIdx.x, jp = blockIdx.y, t = threadIdx.x;
    const int b0 = jp * 2, b1 = b0 + 1;

    const unsigned short* px1a = X + ((size_t)(0 * 8 + b0) * 768 + d) * 2048;
    const unsigned short* pva  = X + ((size_t)(2 * 8 + b0) * 768 + d) * 2048;
    const unsigned short* px1b = X + ((size_t)(0 * 8 + b1) * 768 + d) * 2048;
    const unsigned short* pvb  = X + ((size_t)(2 * 8 + b1) * 768 + d) * 2048;

    // ---- v * x1 gate, b0 then b1 (halved live set), pack pairs into LDS ----
    {
        float w1[4], wv[4];
        #pragma unroll
        for (int j = 0; j < 4; ++j) { w1[j] = x1_s[d * 4 + j]; wv[j] = v_s[d * 4 + j]; }
        const float bc1 = x1_sb[d], bcv = v_sb[d];
        float pa[8];
        {
            float va[8], g[8];
            conv6(pva,  wv, bcv, t, va);
            conv6(px1a, w1, bc1, t, g);
            #pragma unroll
            for (int i = 0; i < 8; ++i) pa[i] = va[i] * g[i];
        }
        {
            float vb[8], g[8];
            conv6(pvb,  wv, bcv, t, vb);
            conv6(px1b, w1, bc1, t, g);
            unsigned vh[8];
            #pragma unroll
            for (int i = 0; i < 8; ++i)
                vh[i] = (unsigned)f2b(pa[i]) | ((unsigned)f2b(vb[i] * g[i]) << 16);
            *(uint4*)(ldsu + 8 * t)     = make_uint4(vh[0], vh[1], vh[2], vh[3]);
            *(uint4*)(ldsu + 8 * t + 4) = make_uint4(vh[4], vh[5], vh[6], vh[7]);
        }
    }
    __syncthreads();

    float2 x[16];
    #pragma unroll
    for (int r = 0; r < 8; ++r) {
        const unsigned u = ldsu[r * 256 + t];
        x[r] = make_float2(b2f_lo(u), b2f_hi(u));
    }
    __syncthreads();

    fft4096_fwd(x, lds, t);

    // pointwise multiply by Kf' (= (FFT(k)+Db)/4096); 4-wide chunks with
    // fences so the compiler doesn't hoist 16 loads into 32 live regs.
    {
        const float2* kf = Kf + (size_t)d * 4096;
        #pragma unroll
        for (int c4 = 0; c4 < 4; ++c4) {
            float2 kr[4];
            #pragma unroll
            for (int j = 0; j < 4; ++j) kr[j] = kf[(c4 * 4 + j) * 256 + t];
            #pragma unroll
            for (int j = 0; j < 4; ++j) x[c4 * 4 + j] = cmul(x[c4 * 4 + j], kr[j]);
            __asm__ __volatile__("" ::: "memory");
        }
    }

    fft4096_inv(x, lds, t);

    // ---- x2 gate: recompute, transpose through LDS, apply, store ----
    __syncthreads();   // all lanes done with inv-FFT's final LDS reads
    {
        const unsigned short* px2a = X + ((size_t)(1 * 8 + b0) * 768 + d) * 2048;
        const unsigned short* px2b = X + ((size_t)(1 * 8 + b1) * 768 + d) * 2048;
        float w2[4];
        #pragma unroll
        for (int j = 0; j < 4; ++j) w2[j] = x2_s[d * 4 + j];
        const float bc2 = x2_sb[d];
        float ga[8], gb[8];
        conv6(px2a, w2, bc2, t, ga);
        conv6(px2b, w2, bc2, t, gb);
        unsigned c2[8];
        #pragma unroll
        for (int i = 0; i < 8; ++i)
            c2[i] = (unsigned)f2b(ga[i]) | ((unsigned)f2b(gb[i]) << 16);
        *(uint4*)(ldsu + 8 * t)     = make_uint4(c2[0], c2[1], c2[2], c2[3]);
        *(uint4*)(ldsu + 8 * t + 4) = make_uint4(c2[4], c2[5], c2[6], c2[7]);
    }
    __syncthreads();

    unsigned short* ya = Y + ((size_t)b0 * 768 + d) * 2048;
    unsigned short* yb = Y + ((size_t)b1 * 768 + d) * 2048;
    #pragma unroll
    for (int n1 = 0; n1 < 8; ++n1) {
        const int l = n1 * 256 + t;
        const unsigned u = ldsu[l];
        ya[l] = f2b(x[n1].x * b2f_lo(u));
        yb[l] = f2b(x[n1].y * b2f_hi(u));
    }
}

// --------------------------------- launch ----------------------------------
extern "C" void kernel_launch(void* const* d_in, const int* in_sizes, int n_in,
                              void* d_out, int out_size, void* d_ws, size_t ws_size,
                              hipStream_t stream)
{
    (void)in_sizes; (void)n_in; (void)out_size; (void)ws_size;
    const float* u      = (const float*)d_in[0];
    const float* in_W   = (const float*)d_in[1];
    const float* in_b   = (const float*)d_in[2];
    const float* out_W  = (const float*)d_in[3];
    const float* out_b  = (const float*)d_in[4];
    const float* x1_s   = (const float*)d_in[5];
    const float* x2_s   = (const float*)d_in[6];
    const float* v_s    = (const float*)d_in[7];
    const float* x1_sb  = (const float*)d_in[8];
    const float* x2_sb  = (const float*)d_in[9];
    const float* v_sb   = (const float*)d_in[10];
    const float* D_bias = (const float*)d_in[11];
    const float* z      = (const float*)d_in[12];
    const float* sf     = (const float*)d_in[13];
    const float* eo     = (const float*)d_in[14];
    const float* eo_b   = (const float*)d_in[15];
    const float* oo1    = (const float*)d_in[16];
    const float* oo1_b  = (const float*)d_in[17];
    const float* oo2    = (const float*)d_in[18];
    const float* oo2_b  = (const float*)d_in[19];
    const float* oh     = (const float*)d_in[20];
    float* out = (float*)d_out;

    char* ws = (char*)d_ws;
    unsigned short* Xbf  = (unsigned short*)(ws + 0);          //  75,497,472 X[3][8][768][2048] bf16
    unsigned short* Ybf  = (unsigned short*)(ws + 75497472);   //  25,165,824 Y[8][768][2048] bf16
    unsigned short* ubYt = (unsigned short*)(ws + 100663296);  //  25,165,824 ub, later aliased as Yt
    unsigned short* Wt   = (unsigned short*)(ws + 125829120);  //   3,538,944 Wt[2304][768] bf16
    unsigned short* W2t  = (unsigned short*)(ws + 129368064);  //   1,179,648 W2t[768][768] bf16
    float*          kfil = (float*)(ws + 130547712);           //   6,291,456 k[768][2048] fp32
    float2*         Kf   = (float2*)(ws + 136839168);          //  25,165,824 K_f[768][16][256] cplx (permuted, (FFT(k)+Db)/4096)

    static int attr_set = 0;
    if (!attr_set) {
        (void)hipFuncSetAttribute(
            reinterpret_cast<const void*>(&gemm_bd_kernel),
            hipFuncAttributeMaxDynamicSharedMemorySize, 49152);
        (void)hipFuncSetAttribute(
            reinterpret_cast<const void*>(&gemm2ph_kernel<256, 192, 4, 2>),
            hipFuncAttributeMaxDynamicSharedMemorySize, 114688);
        attr_set = 1;
    }

    filter_k_kernel<<<512, 256, 0, stream>>>(z, sf, eo, eo_b, oo1, oo1_b, oo2, oo2_b, oh, kfil);
    filter_fft_kernel<<<768, 256, 0, stream>>>(kfil, D_bias, Kf);
    convert_u_kernel<<<12288, 256, 0, stream>>>(u, ubYt);
    transpose_W_kernel<<<dim3(72, 24), 256, 0, stream>>>(in_W, Wt, 768, 2304);
    transpose_W_kernel<<<dim3(24, 24), 256, 0, stream>>>(out_W, W2t, 768, 768);
    // mode 0: 12 row-tiles(192) x 64 col-tiles(256) = 768 blocks = 3.0 rounds
    gemm_bd_kernel<<<dim3(64, 12), 512, 49152, stream>>>(Wt, ubYt, in_b, Xbf);
    fft_conv_kernel<<<dim3(768, 4), 256, 0, stream>>>(Xbf, Kf, x1_s, x2_s, v_s, x1_sb, x2_sb, v_sb, Ybf);
    transpose_Y_kernel<<<12288, 256, 0, stream>>>(Ybf, ubYt);
    // mode 1: 64 row-tiles(256) x 4 col-tiles(192) = 256 blocks = 1.0 round
    gemm2ph_kernel<256, 192, 4, 2><<<dim3(64, 4), 512, 114688, stream>>>(
        ubYt, W2t, out_b, out);
}

// Round 8
// 360.798 us; speedup vs baseline: 1.0813x; 1.0813x over previous
//
#include <hip/hip_runtime.h>

// ---------------------------------------------------------------------------
// FlashMMSequenceMixing (Hyena-style): B=8, L=2048, D=768, ORDER=128, FFT=4096
// R14 -> R15 (consolidation): B-direct mode-0 FAILED (104us vs 65; per-lane
// B loads = 16 cache lines/instr, L2-latency-exposed at 1 blk/CU). Revert to
// the best measured per-kernel configs:
//  - mode 0: R13 8-phase counted-vmcnt gemm8ph<192,256,2,4,0>, 65.0us.
//  - mode 1: R12/R14 2-phase gemm2ph<256,192,4,2> (R13/R14 wall arithmetic
//    shows 2ph beats 8ph by ~10us on this small-N GEMM).
//  - fft_conv / filters / transposes: unchanged (R11/R12 state).
// ---------------------------------------------------------------------------

typedef __bf16 bf16x8 __attribute__((ext_vector_type(8)));
typedef float  f32x4  __attribute__((ext_vector_type(4)));

#define AS1 __attribute__((address_space(1)))
#define AS3 __attribute__((address_space(3)))
#define GLD16(gp, lp) __builtin_amdgcn_global_load_lds((AS1 void*)(void*)(gp), (AS3 void*)(void*)(lp), 16, 0, 0)

// compiler-visible fences (memory clobber pins LDS/global ops to program order)
#define LGKM_BAR       __asm__ __volatile__("s_waitcnt lgkmcnt(0)\n\ts_barrier" ::: "memory")
#define VM_LGKM_BAR(N) __asm__ __volatile__("s_waitcnt vmcnt(" #N ") lgkmcnt(0)\n\ts_barrier" ::: "memory")

__device__ __forceinline__ unsigned short f2b(float f) {
    unsigned u = __builtin_bit_cast(unsigned, f);
    unsigned r = (u + 0x7fffu + ((u >> 16) & 1u)) >> 16;
    return (unsigned short)r;
}
__device__ __forceinline__ float b2f_lo(unsigned u) {
    return __builtin_bit_cast(float, u << 16);
}
__device__ __forceinline__ float b2f_hi(unsigned u) {
    return __builtin_bit_cast(float, u & 0xffff0000u);
}

__device__ __forceinline__ float2 cmul(float2 a, float2 b) {
    return make_float2(a.x * b.x - a.y * b.y, a.x * b.y + a.y * b.x);
}
__device__ __forceinline__ float2 cadd(float2 a, float2 b) { return make_float2(a.x + b.x, a.y + b.y); }
__device__ __forceinline__ float2 csub(float2 a, float2 b) { return make_float2(a.x - b.x, a.y - b.y); }

#define TWO_PI 6.283185307179586f

// ------------------------- 16-point register DFT ---------------------------
#define BFLY(i,j)   { float2 ta=x[i], tb=x[j]; x[i]=cadd(ta,tb); x[j]=csub(ta,tb); }
#define BFLYW(i,j,w){ float2 ta=x[i], tb=x[j]; x[i]=cadd(ta,tb); x[j]=cmul(csub(ta,tb),(w)); }
#define BFLYI(i,j)  { float2 ta=x[i], tb=x[j]; x[i]=cadd(ta,tb); float2 tt=csub(ta,tb); x[j]=make_float2(-dd*tt.y, dd*tt.x); }
#define CSWAP(i,j)  { float2 tt=x[i]; x[i]=x[j]; x[j]=tt; }

template<int DIR, bool UZ>
__device__ __forceinline__ void dft16(float2* x) {
    const float dd = (float)DIR;
    const float C1 = 0.92387953251128674f, S1 = 0.38268343236508977f, R2 = 0.70710678118654752f;
    const float2 W1 = make_float2( C1, dd*S1);
    const float2 W2 = make_float2( R2, dd*R2);
    const float2 W3 = make_float2( S1, dd*C1);
    const float2 W5 = make_float2(-S1, dd*C1);
    const float2 W6 = make_float2(-R2, dd*R2);
    const float2 W7 = make_float2(-C1, dd*S1);
    if (UZ) {
        x[8]  = x[0];
        x[9]  = cmul(x[1], W1);
        x[10] = cmul(x[2], W2);
        x[11] = cmul(x[3], W3);
        x[12] = make_float2(-dd*x[4].y, dd*x[4].x);
        x[13] = cmul(x[5], W5);
        x[14] = cmul(x[6], W6);
        x[15] = cmul(x[7], W7);
    } else {
        BFLY(0,8); BFLYW(1,9,W1); BFLYW(2,10,W2); BFLYW(3,11,W3);
        BFLYI(4,12); BFLYW(5,13,W5); BFLYW(6,14,W6); BFLYW(7,15,W7);
    }
    BFLY(0,4);  BFLYW(1,5,W2);  BFLYI(2,6);   BFLYW(3,7,W6);
    BFLY(8,12); BFLYW(9,13,W2); BFLYI(10,14); BFLYW(11,15,W6);
    BFLY(0,2);  BFLYI(1,3);  BFLY(4,6);   BFLYI(5,7);
    BFLY(8,10); BFLYI(9,11); BFLY(12,14); BFLYI(13,15);
    BFLY(0,1); BFLY(2,3); BFLY(4,5); BFLY(6,7);
    BFLY(8,9); BFLY(10,11); BFLY(12,13); BFLY(14,15);
    CSWAP(1,8); CSWAP(2,4); CSWAP(3,12); CSWAP(5,10); CSWAP(7,14); CSWAP(11,13);
}

// twiddle by power-split: x[4a+b] *= w^(4a) * w^b. 6 complex (12 VGPR) live.
__device__ __forceinline__ void twiddle16(float2* x, float ang) {
    float s, c; __sincosf(ang, &s, &c);
    const float2 u1  = make_float2(c, s);
    const float2 u2  = cmul(u1, u1);
    const float2 u3  = cmul(u2, u1);
    const float2 u4  = cmul(u2, u2);
    const float2 u8  = cmul(u4, u4);
    const float2 u12 = cmul(u8, u4);
    x[1]  = cmul(x[1],  u1);
    x[2]  = cmul(x[2],  u2);
    x[3]  = cmul(x[3],  u3);
    x[4]  = cmul(x[4],  u4);
    x[5]  = cmul(x[5],  cmul(u4, u1));
    x[6]  = cmul(x[6],  cmul(u4, u2));
    x[7]  = cmul(x[7],  cmul(u4, u3));
    x[8]  = cmul(x[8],  u8);
    x[9]  = cmul(x[9],  cmul(u8, u1));
    x[10] = cmul(x[10], cmul(u8, u2));
    x[11] = cmul(x[11], cmul(u8, u3));
    x[12] = cmul(x[12], u12);
    x[13] = cmul(x[13], cmul(u12, u1));
    x[14] = cmul(x[14], cmul(u12, u2));
    x[15] = cmul(x[15], cmul(u12, u3));
}

// physical LDS index (float2 units), XOR-swizzled exact-stride layouts.
__device__ __forceinline__ int ph1(int row, int col) { return row * 256 + (col ^ row); }
__device__ __forceinline__ int ph2(int row, int col) { return row * 16 + (col ^ (row & 15)); }

__device__ __forceinline__ void fft4096_fwd(float2* x, float2* lds, int t) {
    dft16<-1, true>(x);
    twiddle16(x, -(float)t * (TWO_PI / 4096.0f));
    #pragma unroll
    for (int k1 = 0; k1 < 16; ++k1) lds[ph1(k1, t)] = x[k1];
    __syncthreads();
    const int hi = t >> 4, lo = t & 15;
    #pragma unroll
    for (int t1 = 0; t1 < 16; ++t1) x[t1] = lds[ph1(hi, t1 * 16 + lo)];
    dft16<-1, false>(x);
    twiddle16(x, -(float)lo * (TWO_PI / 256.0f));
    __syncthreads();
    #pragma unroll
    for (int k2 = 0; k2 < 16; ++k2) lds[ph2(t, k2)] = x[k2];
    __syncthreads();
    #pragma unroll
    for (int t0 = 0; t0 < 16; ++t0) x[t0] = lds[ph2(hi * 16 + t0, lo)];
    dft16<-1, false>(x);
}

__device__ __forceinline__ void fft4096_inv(float2* x, float2* lds, int t) {
    const int hi = t >> 4, lo = t & 15;
    dft16<1, false>(x);
    __syncthreads();
    #pragma unroll
    for (int t0 = 0; t0 < 16; ++t0) lds[ph2(hi * 16 + t0, lo)] = x[t0];
    __syncthreads();
    #pragma unroll
    for (int k2 = 0; k2 < 16; ++k2) x[k2] = lds[ph2(t, k2)];
    twiddle16(x, (float)lo * (TWO_PI / 256.0f));
    dft16<1, false>(x);
    __syncthreads();
    #pragma unroll
    for (int t1 = 0; t1 < 16; ++t1) lds[ph1(hi, t1 * 16 + lo)] = x[t1];
    __syncthreads();
    #pragma unroll
    for (int k1 = 0; k1 < 16; ++k1) x[k1] = lds[ph1(k1, t)];
    twiddle16(x, (float)t * (TWO_PI / 4096.0f));
    dft16<1, false>(x);
}

// ------------------------------- filter MLP --------------------------------
__global__ __launch_bounds__(256) void filter_k_kernel(
    const float* __restrict__ z, const float* __restrict__ sf,
    const float* __restrict__ eo, const float* __restrict__ eo_b,
    const float* __restrict__ oo1, const float* __restrict__ oo1_b,
    const float* __restrict__ oo2, const float* __restrict__ oo2_b,
    const float* __restrict__ oh, float* __restrict__ kfil)
{
    __shared__ float h3buf[4][128];
    __shared__ float htmp[2][128];
    const int t = threadIdx.x;
    const int l0 = blockIdx.x * 4;
    const int half = t >> 7;
    const int o = t & 127;
    const float sfo = sf[o];
    for (int p = 0; p < 2; ++p) {
        const int li = p * 2 + half;
        const int l = l0 + li;
        float a = eo_b[o];
        #pragma unroll
        for (int e = 0; e < 5; ++e) a += z[l * 5 + e] * eo[e * 128 + o];
        htmp[half][o] = sinf(sfo * a);
        __syncthreads();
        float a2 = oo1_b[o];
        for (int q = 0; q < 128; ++q) a2 += htmp[half][q] * oo1[q * 128 + o];
        const float h2 = sinf(sfo * a2);
        __syncthreads();
        htmp[half][o] = h2;
        __syncthreads();
        float a3 = oo2_b[o];
        for (int q = 0; q < 128; ++q) a3 += htmp[half][q] * oo2[q * 128 + o];
        h3buf[li][o] = sinf(sfo * a3);
        __syncthreads();
    }
    const float MIND = -3.070113457325394f;
    const float MAXD = -15.350567286626972f;
    for (int c = 0; c < 3; ++c) {
        const int h = t + c * 256;
        float acc[4];
        #pragma unroll
        for (int li = 0; li < 4; ++li) acc[li] = 0.f;
        for (int q = 0; q < 128; ++q) {
            const float w = oh[q * 768 + h];
            #pragma unroll
            for (int li = 0; li < 4; ++li) acc[li] += h3buf[li][q] * w;
        }
        const float delta = fabsf(MIND + (MAXD - MIND) * (float)h * (1.0f / 767.0f));
        #pragma unroll
        for (int li = 0; li < 4; ++li) {
            const int l = l0 + li;
            const float tt = (float)l * (1.0f / 2047.0f);
            kfil[h * 2048 + l] = acc[li] * expf(-tt * delta);
        }
    }
}

// --------------------------- filter FFT ------------------------------------
// Stores Kf' = (FFT(k) + D_bias[d]) / 4096 (normalization + skip folded in).
__global__ __launch_bounds__(256) void filter_fft_kernel(
    const float* __restrict__ kfil, const float* __restrict__ D_bias,
    float2* __restrict__ Kf)
{
    __shared__ __align__(16) float2 lds[4096];
    const int d = blockIdx.x, t = threadIdx.x;
    float2 x[16];
    #pragma unroll
    for (int r = 0; r < 8; ++r) x[r] = make_float2(kfil[d * 2048 + r * 256 + t], 0.f);
    fft4096_fwd(x, lds, t);
    const float db = D_bias[d];
    const float s = 1.0f / 4096.0f;
    #pragma unroll
    for (int k3 = 0; k3 < 16; ++k3)
        Kf[d * 4096 + k3 * 256 + t] = make_float2((x[k3].x + db) * s, x[k3].y * s);
}

// --------------------------- conversions/transposes ------------------------
__global__ __launch_bounds__(256) void convert_u_kernel(
    const float* __restrict__ u, unsigned short* __restrict__ ub)
{
    const int g = blockIdx.x * 256 + threadIdx.x;
    const float4 v = ((const float4*)u)[g];
    uint2 o;
    o.x = (unsigned)f2b(v.x) | ((unsigned)f2b(v.y) << 16);
    o.y = (unsigned)f2b(v.z) | ((unsigned)f2b(v.w) << 16);
    ((uint2*)ub)[g] = o;
}

__global__ __launch_bounds__(256) void transpose_W_kernel(
    const float* __restrict__ W, unsigned short* __restrict__ Wt, int K, int N)
{
    __shared__ float tile[32][33];
    const int n0 = blockIdx.x * 32, k0 = blockIdx.y * 32;
    const int tx = threadIdx.x & 31, ty = threadIdx.x >> 5;
    #pragma unroll
    for (int r = 0; r < 4; ++r) {
        const int kk = ty + r * 8;
        tile[kk][tx] = W[(k0 + kk) * N + n0 + tx];
    }
    __syncthreads();
    #pragma unroll
    for (int r = 0; r < 4; ++r) {
        const int nn = ty + r * 8;
        Wt[(n0 + nn) * K + k0 + tx] = f2b(tile[tx][nn]);
    }
}

__global__ __launch_bounds__(256) void transpose_Y_kernel(
    const unsigned short* __restrict__ Y, unsigned short* __restrict__ Yt)
{
    __shared__ unsigned short tile[32][34];
    const int bx = blockIdx.x;
    const int l0 = (bx & 63) * 32;
    const int tmp = bx >> 6;
    const int d0 = (tmp % 24) * 32;
    const int b  = tmp / 24;
    const int tx = threadIdx.x & 31, ty = threadIdx.x >> 5;
    #pragma unroll
    for (int r = 0; r < 4; ++r) {
        const int dd = ty + r * 8;
        tile[dd][tx] = Y[(b * 768 + d0 + dd) * 2048 + l0 + tx];
    }
    __syncthreads();
    #pragma unroll
    for (int r = 0; r < 4; ++r) {
        const int ll = ty + r * 8;
        Yt[(b * 2048 + l0 + ll) * 768 + d0 + tx] = tile[tx][ll];
    }
}

// --------------- bf16 GEMM, mode 0: 8-phase counted-vmcnt ------------------
// 192x256 tile, BK=64, 8 waves (2Mx4N), wave tile 96x64 (R13, 65us).
// Stage/fence windows: see R13 header. Grid (64,12) = 768 blk = 3.0 rounds.
template<int TM, int TN, int WR, int WC>
__global__ __launch_bounds__(512, 2) void gemm8ph_kernel(
    const unsigned short* __restrict__ A,
    const unsigned short* __restrict__ Bm,
    const float* __restrict__ bias,
    unsigned short* __restrict__ outb)
{
    constexpr int MF = TM / WR / 16;
    constexpr int NF = TN / WC / 16;
    constexpr int MH = MF / 2;
    constexpr int NH = NF / 2;
    constexpr int QA = TM / 64;
    constexpr int QB = TN / 64;
    extern __shared__ __align__(16) unsigned short lds[];
    unsigned short* As = lds;                    // [2][TM][64]
    unsigned short* Bs = lds + 2 * TM * 64;      // [2][TN][64]
    const int t = threadIdx.x;
    const int wv = t >> 6, lane = t & 63;
    const int row0 = blockIdx.y * TM;
    const int col0 = blockIdx.x * TN;
    const int wr = wv / WC, wc = wv % WC;
    const int frow = lane & 15, kc = lane >> 4;

    f32x4 acc[MF][NF] = {};

    const int srow = t >> 3;
    const int cdat = (t & 7) ^ (srow & 7);
    const unsigned short* gA = A  + (row0 + srow) * 768 + cdat * 8;
    const unsigned short* gB = Bm + (col0 + srow) * 768 + cdat * 8;

#define STG_Aq(buf, q, kt) GLD16(gA + (q) * 49152 + (kt),                     \
        (char*)As + (buf) * (TM * 128) + (q) * 8192 + wv * 1024)
#define STG_Bq(buf, q, kt) GLD16(gB + (q) * 49152 + (kt),                     \
        (char*)Bs + (buf) * (TN * 128) + (q) * 8192 + wv * 1024)
#define STG_A1(buf, kt) { STG_Aq(buf, 0, kt); STG_Aq(buf, 1, kt); }
#define STG_A2(buf, kt) { _Pragma("unroll") for (int q = 2; q < QA; ++q) STG_Aq(buf, q, kt); }
#define STG_B1(buf, kt) { STG_Bq(buf, 0, kt); STG_Bq(buf, 1, kt); }
#define STG_B2(buf, kt) { _Pragma("unroll") for (int q = 2; q < QB; ++q) STG_Bq(buf, q, kt); }
#define FENCE_QB { if constexpr (QB == 4) { VM_LGKM_BAR(4); } else { VM_LGKM_BAR(3); } }

    bf16x8 aF[MH][2], bN0[NH][2], bN1[NH][2];

#define READ_A(buf, mh)                                                        \
    _Pragma("unroll") for (int m = 0; m < MH; ++m) {                           \
        const int r = wr * (TM / WR) + ((mh) * MH + m) * 16 + frow;            \
        aF[m][0] = *(const bf16x8*)(As + (buf) * (TM * 64) + r * 64 +          \
                                    (((0 + kc) ^ (r & 7)) << 3));              \
        aF[m][1] = *(const bf16x8*)(As + (buf) * (TM * 64) + r * 64 +          \
                                    (((4 + kc) ^ (r & 7)) << 3));              \
    }
#define READ_B(buf, nh, arr)                                                   \
    _Pragma("unroll") for (int n = 0; n < NH; ++n) {                           \
        const int r = wc * (TN / WC) + ((nh) * NH + n) * 16 + frow;            \
        arr[n][0] = *(const bf16x8*)(Bs + (buf) * (TN * 64) + r * 64 +         \
                                     (((0 + kc) ^ (r & 7)) << 3));             \
        arr[n][1] = *(const bf16x8*)(Bs + (buf) * (TN * 64) + r * 64 +         \
                                     (((4 + kc) ^ (r & 7)) << 3));             \
    }
#define MFMA_Q(mh, nh, arr)                                                    \
    __builtin_amdgcn_s_setprio(1);                                             \
    _Pragma("unroll") for (int m = 0; m < MH; ++m)                             \
    _Pragma("unroll") for (int n = 0; n < NH; ++n)                             \
    _Pragma("unroll") for (int ks = 0; ks < 2; ++ks)                           \
        acc[(mh) * MH + m][(nh) * NH + n] =                                    \
            __builtin_amdgcn_mfma_f32_16x16x32_bf16(                           \
                aF[m][ks], arr[n][ks], acc[(mh) * MH + m][(nh) * NH + n],      \
                0, 0, 0);                                                      \
    __builtin_amdgcn_s_setprio(0);

    // prologue: buf0 <- tile 0 (full, oldest QA+QB), buf1.B <- tile 1
    STG_A1(0, 0); STG_A2(0, 0); STG_B1(0, 0); STG_B2(0, 0);
    STG_B1(1, 64); STG_B2(1, 64);
    FENCE_QB;   // all but newest QB (buf1.B) landed = tile 0 complete

    #pragma unroll 1
    for (int i = 0; i < 5; ++i) {
        const int k1 = (2 * i + 1) * 64, k2 = (2 * i + 2) * 64, k3 = (2 * i + 3) * 64;
        // P1: Qa(buf0)
        READ_A(0, 0); READ_B(0, 0, bN0);
        STG_A1(1, k1);
        MFMA_Q(0, 0, bN0);
        LGKM_BAR;
        // P2: Qb(buf0)
        READ_B(0, 1, bN1);
        STG_A2(1, k1);
        MFMA_Q(0, 1, bN1);
        LGKM_BAR;
        // P3: Qc(buf0)
        READ_A(0, 1);
        STG_B1(0, k2);
        MFMA_Q(1, 1, bN1);
        LGKM_BAR;
        // P4: Qd(buf0) — register reuse only
        STG_B2(0, k2);
        MFMA_Q(1, 0, bN0);
        FENCE_QB;
        // P5: Qa(buf1)
        READ_A(1, 0); READ_B(1, 0, bN0);
        STG_A1(0, k2);
        MFMA_Q(0, 0, bN0);
        LGKM_BAR;
        // P6: Qb(buf1)
        READ_B(1, 1, bN1);
        STG_A2(0, k2);
        MFMA_Q(0, 1, bN1);
        LGKM_BAR;
        // P7: Qc(buf1)
        READ_A(1, 1);
        STG_B1(1, k3);
        MFMA_Q(1, 1, bN1);
        LGKM_BAR;
        // P8: Qd(buf1)
        STG_B2(1, k3);
        MFMA_Q(1, 0, bN0);
        FENCE_QB;
    }

    // epilogue: tiles 10 (buf0) and 11 (buf1); only buf1.A@11 still to stage
    {
        READ_A(0, 0); READ_B(0, 0, bN0);
        STG_A1(1, 704);
        MFMA_Q(0, 0, bN0);
        LGKM_BAR;
        READ_B(0, 1, bN1);
        STG_A2(1, 704);
        MFMA_Q(0, 1, bN1);
        LGKM_BAR;
        READ_A(0, 1);
        MFMA_Q(1, 1, bN1);
        LGKM_BAR;
        MFMA_Q(1, 0, bN0);
        VM_LGKM_BAR(0);   // tile 11 landed; vmcnt==0 from here on
        READ_A(1, 0); READ_B(1, 0, bN0); READ_B(1, 1, bN1);
        MFMA_Q(0, 0, bN0);
        MFMA_Q(0, 1, bN1);
        READ_A(1, 1);
        MFMA_Q(1, 1, bN1);
        MFMA_Q(1, 0, bN0);
    }
#undef READ_A
#undef READ_B
#undef MFMA_Q
#undef STG_Aq
#undef STG_Bq
#undef STG_A1
#undef STG_A2
#undef STG_B1
#undef STG_B2
#undef FENCE_QB

    // bf16 out to X[part][b][768][2048]
    {
        const int part = row0 / 768;       // 192 | 768: no straddle
        const int bb = col0 / 2048;        // 256 | 2048
        unsigned short* Xp = outb + (size_t)(part * 8 + bb) * 768 * 2048;
        const int drow0 = row0 - part * 768 + wr * (TM / WR) + kc * 4;
        const int lcol0 = col0 - bb * 2048 + wc * (TN / WC) + frow;
        #pragma unroll
        for (int m = 0; m < MF; ++m) {
            #pragma unroll
            for (int rr = 0; rr < 4; ++rr) {
                const int dd = drow0 + m * 16 + rr;
                const float bn = bias[row0 + wr * (TM / WR) + kc * 4 + m * 16 + rr];
                #pragma unroll
                for (int n = 0; n < NF; ++n)
                    Xp[dd * 2048 + lcol0 + n * 16] = f2b(acc[m][n][rr] + bn);
            }
        }
    }
}

// --------------------- bf16 GEMM, mode 1: 2-phase --------------------------
// 256x192 tile, BK=64, 8 waves (4Mx2N). Grid (64,4) = 256 blk = 1.0 round.
template<int TM, int TN, int WR, int WC>
__global__ __launch_bounds__(512, 2) void gemm2ph_kernel(
    const unsigned short* __restrict__ A,
    const unsigned short* __restrict__ Bm,
    const float* __restrict__ bias,
    float* __restrict__ outf)
{
    constexpr int MF = TM / WR / 16;
    constexpr int NF = TN / WC / 16;
    constexpr int QA = TM / 64;
    constexpr int QB = TN / 64;
    extern __shared__ __align__(16) unsigned short lds[];
    unsigned short* As = lds;                    // [2][TM][64]
    unsigned short* Bs = lds + 2 * TM * 64;      // [2][TN][64]
    const int t = threadIdx.x;
    const int wv = t >> 6, lane = t & 63;
    const int row0 = blockIdx.x * TM;
    const int col0 = blockIdx.y * TN;
    const int wr = wv / WC, wc = wv % WC;
    const int frow = lane & 15, kc = lane >> 4;

    f32x4 acc[MF][NF] = {};

    const int srow = t >> 3;
    const int cdat = (t & 7) ^ (srow & 7);
    const unsigned short* gA = A  + (row0 + srow) * 768 + cdat * 8;
    const unsigned short* gB = Bm + (col0 + srow) * 768 + cdat * 8;

#define STAGE(buf, kt)                                                        \
    {                                                                         \
        _Pragma("unroll") for (int q = 0; q < QA; ++q)                        \
            GLD16(gA + q * 49152 + (kt) * 64,                                 \
                  (char*)As + (buf) * (TM * 128) + q * 8192 + wv * 1024);     \
        _Pragma("unroll") for (int q = 0; q < QB; ++q)                        \
            GLD16(gB + q * 49152 + (kt) * 64,                                 \
                  (char*)Bs + (buf) * (TN * 128) + q * 8192 + wv * 1024);     \
    }

#define HALF(buf, ks)                                                         \
    {                                                                         \
        bf16x8 aF[MF], bF[NF];                                                \
        _Pragma("unroll") for (int m = 0; m < MF; ++m) {                      \
            const int r = wr * (TM / WR) + m * 16 + frow;                     \
            aF[m] = *(const bf16x8*)(As + (buf) * (TM * 64) + r * 64 +        \
                                     ((((ks) * 4 + kc) ^ (r & 7)) << 3));     \
        }                                                                     \
        _Pragma("unroll") for (int n = 0; n < NF; ++n) {                      \
            const int r = wc * (TN / WC) + n * 16 + frow;                     \
            bF[n] = *(const bf16x8*)(Bs + (buf) * (TN * 64) + r * 64 +        \
                                     ((((ks) * 4 + kc) ^ (r & 7)) << 3));     \
        }                                                                     \
        __builtin_amdgcn_s_setprio(1);                                        \
        _Pragma("unroll") for (int m = 0; m < MF; ++m)                        \
        _Pragma("unroll") for (int n = 0; n < NF; ++n)                        \
            acc[m][n] = __builtin_amdgcn_mfma_f32_16x16x32_bf16(              \
                aF[m], bF[n], acc[m][n], 0, 0, 0);                            \
        __builtin_amdgcn_s_setprio(0);                                        \
    }

    STAGE(0, 0);
    STAGE(1, 1);
    VM_LGKM_BAR(7);            // oldest QA+QB(=7) = tile 0 landed

    HALF(0, 0); HALF(0, 1);
    VM_LGKM_BAR(0);            // tile 1 landed; buf0 readers done

    #pragma unroll 1
    for (int kt = 1; kt <= 9; kt += 2) {
        STAGE(0, kt + 1);
        HALF(1, 0); HALF(1, 1);
        VM_LGKM_BAR(0);
        STAGE(1, kt + 2);
        HALF(0, 0); HALF(0, 1);
        VM_LGKM_BAR(0);
    }

    HALF(1, 0); HALF(1, 1);
#undef STAGE
#undef HALF

    #pragma unroll
    for (int m = 0; m < MF; ++m) {
        #pragma unroll
        for (int rr = 0; rr < 4; ++rr) {
            const int mm = row0 + wr * (TM / WR) + kc * 4 + m * 16 + rr;
            #pragma unroll
            for (int n = 0; n < NF; ++n) {
                const int nn = col0 + wc * (TN / WC) + n * 16 + frow;
                outf[(size_t)mm * 768 + nn] = acc[m][n][rr] + bias[nn];
            }
        }
    }
}

// --------------------- fused conv4 + gate + FFT conv -----------------------
__device__ __forceinline__ void conv6(const unsigned short* __restrict__ p,
                                      const float* w, float bias, int t, float* out8)
{
    const uint4 m = *(const uint4*)(p + 8 * t);
    uint2 q = make_uint2(0u, 0u);
    if (t) q = *(const uint2*)(p + 8 * t - 4);
    float s[12];
    s[0] = b2f_lo(q.x); s[1] = b2f_hi(q.x); s[2] = b2f_lo(q.y); s[3] = b2f_hi(q.y);
    s[4] = b2f_lo(m.x); s[5] = b2f_hi(m.x); s[6] = b2f_lo(m.y); s[7] = b2f_hi(m.y);
    s[8] = b2f_lo(m.z); s[9] = b2f_hi(m.z); s[10] = b2f_lo(m.w); s[11] = b2f_hi(m.w);
    #pragma unroll
    for (int i = 0; i < 8; ++i)
        out8[i] = bias + w[0] * s[i + 1] + w[1] * s[i + 2] + w[2] * s[i + 3] + w[3] * s[i + 4];
}

// grid (768, 4): x=d (same-d blocks 768 apart -> same XCD -> Kf L2 reuse)
__global__ __launch_bounds__(256) void fft_conv_kernel(
    const unsigned short* __restrict__ X, const float2* __restrict__ Kf,
    const float* __restrict__ x1_s, const float* __restrict__ x2_s, const float* __restrict__ v_s,
    const float* __restrict__ x1_sb, const float* __restrict__ x2_sb, const float* __restrict__ v_sb,
    unsigned short* __restrict__ Y)
{
    __shared__ __align__(16) float2 lds[4096];
    unsigned* ldsu = (unsigned*)lds;
    const int d = blockIdx.x, jp = blockIdx.y, t = threadIdx.x;
    const int b0 = jp * 2, b1 = b0 + 1;

    const unsigned short* px1a = X + ((size_t)(0 * 8 + b0) * 768 + d) * 2048;
    const unsigned short* pva  = X + ((size_t)(2 * 8 + b0) * 768 + d) * 2048;
    const unsigned short* px1b = X + ((size_t)(0 * 8 + b1) * 768 + d) * 2048;
    const unsigned short* pvb  = X + ((size_t)(2 * 8 + b1) * 768 + d) * 2048;

    // ---- v * x1 gate, b0 then b1 (halved live set), pack pairs into LDS ----
    {
        float w1[4], wv[4];
        #pragma unroll
        for (int j = 0; j < 4; ++j) { w1[j] = x1_s[d * 4 + j]; wv[j] = v_s[d * 4 + j]; }
        const float bc1 = x1_sb[d], bcv = v_sb[d];
        float pa[8];
        {
            float va[8], g[8];
            conv6(pva,  wv, bcv, t, va);
            conv6(px1a, w1, bc1, t, g);
            #pragma unroll
            for (int i = 0; i < 8; ++i) pa[i] = va[i] * g[i];
        }
        {
            float vb[8], g[8];
            conv6(pvb,  wv, bcv, t, vb);
            conv6(px1b, w1, bc1, t, g);
            unsigned vh[8];
            #pragma unroll
            for (int i = 0; i < 8; ++i)
                vh[i] = (unsigned)f2b(pa[i]) | ((unsigned)f2b(vb[i] * g[i]) << 16);
            *(uint4*)(ldsu + 8 * t)     = make_uint4(vh[0], vh[1], vh[2], vh[3]);
            *(uint4*)(ldsu + 8 * t + 4) = make_uint4(vh[4], vh[5], vh[6], vh[7]);
        }
    }
    __syncthreads();

    float2 x[16];
    #pragma unroll
    for (int r = 0; r < 8; ++r) {
        const unsigned u = ldsu[r * 256 + t];
        x[r] = make_float2(b2f_lo(u), b2f_hi(u));
    }
    __syncthreads();

    fft4096_fwd(x, lds, t);

    // pointwise multiply by Kf' (= (FFT(k)+Db)/4096); 4-wide chunks with
    // fences so the compiler doesn't hoist 16 loads into 32 live regs.
    {
        const float2* kf = Kf + (size_t)d * 4096;
        #pragma unroll
        for (int c4 = 0; c4 < 4; ++c4) {
            float2 kr[4];
            #pragma unroll
            for (int j = 0; j < 4; ++j) kr[j] = kf[(c4 * 4 + j) * 256 + t];
            #pragma unroll
            for (int j = 0; j < 4; ++j) x[c4 * 4 + j] = cmul(x[c4 * 4 + j], kr[j]);
            __asm__ __volatile__("" ::: "memory");
        }
    }

    fft4096_inv(x, lds, t);

    // ---- x2 gate: recompute, transpose through LDS, apply, store ----
    __syncthreads();   // all lanes done with inv-FFT's final LDS reads
    {
        const unsigned short* px2a = X + ((size_t)(1 * 8 + b0) * 768 + d) * 2048;
        const unsigned short* px2b = X + ((size_t)(1 * 8 + b1) * 768 + d) * 2048;
        float w2[4];
        #pragma unroll
        for (int j = 0; j < 4; ++j) w2[j] = x2_s[d * 4 + j];
        const float bc2 = x2_sb[d];
        float ga[8], gb[8];
        conv6(px2a, w2, bc2, t, ga);
        conv6(px2b, w2, bc2, t, gb);
        unsigned c2[8];
        #pragma unroll
        for (int i = 0; i < 8; ++i)
            c2[i] = (unsigned)f2b(ga[i]) | ((unsigned)f2b(gb[i]) << 16);
        *(uint4*)(ldsu + 8 * t)     = make_uint4(c2[0], c2[1], c2[2], c2[3]);
        *(uint4*)(ldsu + 8 * t + 4) = make_uint4(c2[4], c2[5], c2[6], c2[7]);
    }
    __syncthreads();

    unsigned short* ya = Y + ((size_t)b0 * 768 + d) * 2048;
    unsigned short* yb = Y + ((size_t)b1 * 768 + d) * 2048;
    #pragma unroll
    for (int n1 = 0; n1 < 8; ++n1) {
        const int l = n1 * 256 + t;
        const unsigned u = ldsu[l];
        ya[l] = f2b(x[n1].x * b2f_lo(u));
        yb[l] = f2b(x[n1].y * b2f_hi(u));
    }
}

// --------------------------------- launch ----------------------------------
extern "C" void kernel_launch(void* const* d_in, const int* in_sizes, int n_in,
                              void* d_out, int out_size, void* d_ws, size_t ws_size,
                              hipStream_t stream)
{
    (void)in_sizes; (void)n_in; (void)out_size; (void)ws_size;
    const float* u      = (const float*)d_in[0];
    const float* in_W   = (const float*)d_in[1];
    const float* in_b   = (const float*)d_in[2];
    const float* out_W  = (const float*)d_in[3];
    const float* out_b  = (const float*)d_in[4];
    const float* x1_s   = (const float*)d_in[5];
    const float* x2_s   = (const float*)d_in[6];
    const float* v_s    = (const float*)d_in[7];
    const float* x1_sb  = (const float*)d_in[8];
    const float* x2_sb  = (const float*)d_in[9];
    const float* v_sb   = (const float*)d_in[10];
    const float* D_bias = (const float*)d_in[11];
    const float* z      = (const float*)d_in[12];
    const float* sf     = (const float*)d_in[13];
    const float* eo     = (const float*)d_in[14];
    const float* eo_b   = (const float*)d_in[15];
    const float* oo1    = (const float*)d_in[16];
    const float* oo1_b  = (const float*)d_in[17];
    const float* oo2    = (const float*)d_in[18];
    const float* oo2_b  = (const float*)d_in[19];
    const float* oh     = (const float*)d_in[20];
    float* out = (float*)d_out;

    char* ws = (char*)d_ws;
    unsigned short* Xbf  = (unsigned short*)(ws + 0);          //  75,497,472 X[3][8][768][2048] bf16
    unsigned short* Ybf  = (unsigned short*)(ws + 75497472);   //  25,165,824 Y[8][768][2048] bf16
    unsigned short* ubYt = (unsigned short*)(ws + 100663296);  //  25,165,824 ub, later aliased as Yt
    unsigned short* Wt   = (unsigned short*)(ws + 125829120);  //   3,538,944 Wt[2304][768] bf16
    unsigned short* W2t  = (unsigned short*)(ws + 129368064);  //   1,179,648 W2t[768][768] bf16
    float*          kfil = (float*)(ws + 130547712);           //   6,291,456 k[768][2048] fp32
    float2*         Kf   = (float2*)(ws + 136839168);          //  25,165,824 K_f[768][16][256] cplx (permuted, (FFT(k)+Db)/4096)

    static int attr_set = 0;
    if (!attr_set) {
        (void)hipFuncSetAttribute(
            reinterpret_cast<const void*>(&gemm8ph_kernel<192, 256, 2, 4>),
            hipFuncAttributeMaxDynamicSharedMemorySize, 114688);
        (void)hipFuncSetAttribute(
            reinterpret_cast<const void*>(&gemm2ph_kernel<256, 192, 4, 2>),
            hipFuncAttributeMaxDynamicSharedMemorySize, 114688);
        attr_set = 1;
    }

    filter_k_kernel<<<512, 256, 0, stream>>>(z, sf, eo, eo_b, oo1, oo1_b, oo2, oo2_b, oh, kfil);
    filter_fft_kernel<<<768, 256, 0, stream>>>(kfil, D_bias, Kf);
    convert_u_kernel<<<12288, 256, 0, stream>>>(u, ubYt);
    transpose_W_kernel<<<dim3(72, 24), 256, 0, stream>>>(in_W, Wt, 768, 2304);
    transpose_W_kernel<<<dim3(24, 24), 256, 0, stream>>>(out_W, W2t, 768, 768);
    // mode 0: 12 row-tiles(192) x 64 col-tiles(256) = 768 blocks = 3.0 rounds
    gemm8ph_kernel<192, 256, 2, 4><<<dim3(64, 12), 512, 114688, stream>>>(
        Wt, ubYt, in_b, Xbf);
    fft_conv_kernel<<<dim3(768, 4), 256, 0, stream>>>(Xbf, Kf, x1_s, x2_s, v_s, x1_sb, x2_sb, v_sb, Ybf);
    transpose_Y_kernel<<<12288, 256, 0, stream>>>(Ybf, ubYt);
    // mode 1: 64 row-tiles(256) x 4 col-tiles(192) = 256 blocks = 1.0 round
    gemm2ph_kernel<256, 192, 4, 2><<<dim3(64, 4), 512, 114688, stream>>>(
        ubYt, W2t, out_b, out);
}